// Round 6
// baseline (445.071 us; speedup 1.0000x reference)
//
#include <hip/hip_runtime.h>
#include <hip/hip_bf16.h>
#include <math.h>

#define Gn 16000
#define Bn 4096
#define Ln 64
#define Sn 20000

typedef __attribute__((ext_vector_type(8))) short bf16x8;   // 8 bf16 = 4 VGPRs
typedef __attribute__((ext_vector_type(4))) float f32x4;    // MFMA C/D

// ---------- device math helpers ----------

__device__ __forceinline__ float softplus_precise(float z) {
    return fmaxf(z, 0.0f) + log1pf(__expf(-fabsf(z)));
}

// accurate lgamma for z>0 (shift-8 Stirling), used only for the 100-entry table
__device__ __forceinline__ float lgamma_pos8(float z) {
    float p = z * (z + 1.f) * (z + 2.f) * (z + 3.f)
                * (z + 4.f) * (z + 5.f) * (z + 6.f) * (z + 7.f);
    float w = z + 8.f;
    return (w - 0.5f) * __logf(w) - w + 0.9189385332046727f
           + __fdividef(1.0f, 12.0f * w) - __logf(p);
}

__device__ __forceinline__ unsigned short f2bf(float f) {
    union { float f; unsigned int u; } v; v.f = f;
    unsigned int r = v.u + 0x7fff + ((v.u >> 16) & 1);   // RNE
    return (unsigned short)(r >> 16);
}

// ---------- precompute kernels ----------

// One thread per (g,l): rhB [Gn][64] bf16. Threads idx<Gn also do eps/lsp1/lsn.
// lsp1[g] = log_sigmoid(px_o[g]) - 1   (the -1 folds Stirling's -x term)
__global__ void prep_genes(const float* __restrict__ W,
                           const float* __restrict__ px_o,
                           const float* __restrict__ eta,
                           const float* __restrict__ beta,
                           unsigned short* __restrict__ rhB,
                           float* __restrict__ lsp1,
                           float* __restrict__ lsn,
                           float* __restrict__ eps) {
    int idx = blockIdx.x * 256 + threadIdx.x;   // Gn*64 total, exact
    int g = idx >> 6;
    float bsp = softplus_precise(beta[g]);
    rhB[idx] = f2bf(bsp * softplus_precise(W[idx]));   // W row-major [G][L]
    if (idx < Gn) {
        eps[idx] = softplus_precise(eta[idx]);
        float o = px_o[idx];
        lsp1[idx] = -softplus_precise(-o) - 1.0f;   // log_sigmoid(o) - 1
        lsn[idx]  = -softplus_precise(o);           // log_sigmoid(-o)
    }
}

__global__ void prep_spots(const float* __restrict__ V,
                           const int* __restrict__ ind_x,
                           unsigned short* __restrict__ vBg,
                           float* __restrict__ v64) {
    int idx = blockIdx.x * 256 + threadIdx.x;   // Bn*64 total, exact
    int b = idx >> 6, l = idx & 63;
    int s = ind_x[b];
    vBg[idx] = f2bf(softplus_precise(V[l * Sn + s]));
    if (idx < Bn) {
        int s2 = ind_x[idx];
        v64[idx] = softplus_precise(V[Ln * Sn + s2]);
    }
}

// prior: parallel, atomicAdd into out[Bn+1] (out pre-zeroed by memset)
__global__ void prior_kernel(const float* __restrict__ eta, float* __restrict__ out) {
    int idx = blockIdx.x * 256 + threadIdx.x;
    float s = 0.f;
    if (idx < Gn) {
        float e = eta[idx];
        s = 0.9189385332046727f + 0.5f * e * e;
    }
    #pragma unroll
    for (int off = 32; off; off >>= 1) s += __shfl_xor(s, off, 64);
    __shared__ float red[4];
    if ((threadIdx.x & 63) == 0) red[threadIdx.x >> 6] = s;
    __syncthreads();
    if (threadIdx.x == 0) atomicAdd(&out[Bn + 1], red[0] + red[1] + red[2] + red[3]);
}

// ---------- main kernel: barrier-free, fragments direct from global ----------
//
// term = lgamma(x+r) - lgamma(r) - lgamma(x+1) + x*lsp + r*lsn
//      ~= (s-0.5)ln s - (r-0.5)ln r + x*(lsp-1) + r*lsn - lfact[x],  s = r+x
//
// No LDS staging / no heavyweight barrier: MFMA A/B fragments are 16B/lane
// contiguous slices of vBg (0.5 MB) and rhB (2 MB), both L1/L2-resident.
// The only __syncthreads gates the VALU-computed lfact table (no VMEM in
// flight -> trivial drain). Waves are fully decoupled, ~42 loads of MLP each.

__global__ __launch_bounds__(256, 4) void main_kernel(
    const int*            __restrict__ x,
    const unsigned short* __restrict__ rhB,
    const unsigned short* __restrict__ vBg,
    const float*          __restrict__ v64,
    const float*          __restrict__ lsp1g,
    const float*          __restrict__ lsng,
    const float*          __restrict__ epsg,
    float*                __restrict__ out) {
    __shared__ float lfact[100];

    const int tid = threadIdx.x;
    if (tid < 100) lfact[tid] = lgamma_pos8((float)tid + 1.0f);
    __syncthreads();   // drains nothing: no VMEM issued yet

    const int g0 = blockIdx.x * 64;
    const int b0 = blockIdx.y * 64;
    const int wave = tid >> 6, lane = tid & 63;
    const int quad = lane >> 4, ln = lane & 15;
    const int mrow  = wave * 16 + ln;              // A-fragment m index
    const int brow0 = b0 + wave * 16 + quad * 4;   // C rows for this lane

    // A fragments: vBg row (b0+mrow), 16B slices at quad*8 (+kb*32)
    const unsigned short* aPtr = vBg + (size_t)(b0 + mrow) * 64 + quad * 8;
    bf16x8 af0 = *(const bf16x8*)(aPtr);
    bf16x8 af1 = *(const bf16x8*)(aPtr + 32);

    // B fragments: rhB row (g0+nb*16+ln), same slice pattern
    const unsigned short* bPtr = rhB + (size_t)(g0 + ln) * 64 + quad * 8;
    bf16x8 bf_[4][2];
    #pragma unroll
    for (int nb = 0; nb < 4; nb++) {
        bf_[nb][0] = *(const bf16x8*)(bPtr + nb * 1024);
        bf_[nb][1] = *(const bf16x8*)(bPtr + nb * 1024 + 32);
    }

    // x tile: 16 dwords/thread
    int xv[4][4];
    #pragma unroll
    for (int r = 0; r < 4; r++) {
        const int* xp = x + (size_t)(brow0 + r) * Gn + g0 + ln;
        #pragma unroll
        for (int nb = 0; nb < 4; nb++) xv[nb][r] = xp[nb * 16];
    }

    // v64 rows + per-gene constants (L1-resident)
    float vvr[4];
    #pragma unroll
    for (int r = 0; r < 4; r++) vvr[r] = v64[brow0 + r];
    float lsp1v[4], lsnv[4], ev4[4];
    #pragma unroll
    for (int nb = 0; nb < 4; nb++) {
        int g = g0 + nb * 16 + ln;
        lsp1v[nb] = lsp1g[g];
        lsnv[nb]  = lsng[g];
        ev4[nb]   = epsg[g];
    }

    f32x4 acc[4];
    #pragma unroll
    for (int nb = 0; nb < 4; nb++) acc[nb] = (f32x4){0.f, 0.f, 0.f, 0.f};
    #pragma unroll
    for (int nb = 0; nb < 4; nb++) {
        acc[nb] = __builtin_amdgcn_mfma_f32_16x16x32_bf16(af0, bf_[nb][0], acc[nb], 0, 0, 0);
        acc[nb] = __builtin_amdgcn_mfma_f32_16x16x32_bf16(af1, bf_[nb][1], acc[nb], 0, 0, 0);
    }

    float rowpart[4] = {0.f, 0.f, 0.f, 0.f};
    #pragma unroll
    for (int nb = 0; nb < 4; nb++) {
        #pragma unroll
        for (int r = 0; r < 4; r++) {
            const float rr = fmaf(ev4[nb], vvr[r], acc[nb][r]);   // + eps*v64, fp32
            const int   xi = xv[nb][r];
            const float xf = (float)xi;
            const float s  = rr + xf;
            float t = fmaf(s - 0.5f, __logf(s), -lfact[xi]);
            t = fmaf(-(rr - 0.5f), __logf(rr), t);
            t = fmaf(xf, lsp1v[nb], t);
            t = fmaf(rr, lsnv[nb], t);
            rowpart[r] += t;
        }
    }

    // reduce over the 16 gene-lanes of each quad, one atomic per row
    #pragma unroll
    for (int r = 0; r < 4; r++) {
        float v = rowpart[r];
        v += __shfl_xor(v, 1, 64);
        v += __shfl_xor(v, 2, 64);
        v += __shfl_xor(v, 4, 64);
        v += __shfl_xor(v, 8, 64);
        if (ln == 0) atomicAdd(&out[brow0 + r], -v);
    }
}

// ---------- launch ----------

extern "C" void kernel_launch(void* const* d_in, const int* in_sizes, int n_in,
                              void* d_out, int out_size, void* d_ws, size_t ws_size,
                              hipStream_t stream) {
    const int*   x     = (const int*)d_in[0];
    const int*   ind_x = (const int*)d_in[2];
    const float* W     = (const float*)d_in[3];
    const float* px_o  = (const float*)d_in[4];
    const float* eta   = (const float*)d_in[5];
    const float* V     = (const float*)d_in[6];
    const float* beta  = (const float*)d_in[7];
    float* out = (float*)d_out;

    // ws layout (bytes):
    char* wsb = (char*)d_ws;
    unsigned short* rhB  = (unsigned short*)(wsb);                    // Gn*64*2 = 2,048,000
    unsigned short* vBg  = (unsigned short*)(wsb + 2048000);          // Bn*64*2 =   524,288
    float*          v64  = (float*)(wsb + 2572288);                   // Bn*4    =    16,384
    float*          lsp1 = (float*)(wsb + 2588672);                   // Gn*4
    float*          lsn  = (float*)(wsb + 2652672);
    float*          eps  = (float*)(wsb + 2716672);

    // zero loss accumulators AND the two scalar slots (prior uses atomicAdd)
    hipMemsetAsync(d_out, 0, (Bn + 2) * sizeof(float), stream);

    prep_genes<<<(Gn * 64) / 256, 256, 0, stream>>>(W, px_o, eta, beta, rhB, lsp1, lsn, eps);
    prep_spots<<<(Bn * 64) / 256, 256, 0, stream>>>(V, ind_x, vBg, v64);
    prior_kernel<<<(Gn + 255) / 256, 256, 0, stream>>>(eta, out);

    dim3 grid(Gn / 64, Bn / 64);   // 250 x 64
    main_kernel<<<grid, 256, 0, stream>>>(x, rhB, vBg, v64, lsp1, lsn, eps, out);
}

// Round 7
// 442.430 us; speedup vs baseline: 1.0060x; 1.0060x over previous
//
#include <hip/hip_runtime.h>
#include <hip/hip_bf16.h>
#include <math.h>

#define Gn 16000
#define Bn 4096
#define Ln 64
#define Sn 20000

typedef __attribute__((ext_vector_type(8))) short bf16x8;   // 8 bf16 = 4 VGPRs
typedef __attribute__((ext_vector_type(4))) float f32x4;    // MFMA C/D

// ---------- device math helpers ----------

__device__ __forceinline__ float softplus_precise(float z) {
    return fmaxf(z, 0.0f) + log1pf(__expf(-fabsf(z)));
}

// accurate lgamma for z>0 (shift-8 Stirling), used only for the 100-entry table
__device__ __forceinline__ float lgamma_pos8(float z) {
    float p = z * (z + 1.f) * (z + 2.f) * (z + 3.f)
                * (z + 4.f) * (z + 5.f) * (z + 6.f) * (z + 7.f);
    float w = z + 8.f;
    return (w - 0.5f) * __logf(w) - w + 0.9189385332046727f
           + __fdividef(1.0f, 12.0f * w) - __logf(p);
}

__device__ __forceinline__ unsigned short f2bf(float f) {
    union { float f; unsigned int u; } v; v.f = f;
    unsigned int r = v.u + 0x7fff + ((v.u >> 16) & 1);   // RNE
    return (unsigned short)(r >> 16);
}

// ---------- precompute kernels ----------
//
// GENE PERMUTATION: within each 64-gene block, gene with in-block index
// j = ln*4 + nb is stored at MFMA column c = nb*16 + ln ( = (j&3)*16 + (j>>2) ).
// This makes each lane's 4 output columns = 4 CONSECUTIVE genes in natural
// order, so x / lsp1 / lsn / eps all load as one dwordx4 per group.
// lsp1/lsn/eps stay in NATURAL gene order (lane reads g0+ln*4 .. +3).

__global__ void prep_genes(const float* __restrict__ W,
                           const float* __restrict__ px_o,
                           const float* __restrict__ eta,
                           const float* __restrict__ beta,
                           unsigned short* __restrict__ rhB,
                           float* __restrict__ lsp1,
                           float* __restrict__ lsn,
                           float* __restrict__ eps) {
    int idx = blockIdx.x * 256 + threadIdx.x;   // Gn*64 total, exact
    int g = idx >> 6, l = idx & 63;
    int j = g & 63, gb = g & ~63;
    int c = (j & 3) * 16 + (j >> 2);            // permuted MFMA column
    float bsp = softplus_precise(beta[g]);
    rhB[(size_t)(gb + c) * 64 + l] = f2bf(bsp * softplus_precise(W[idx]));
    if (idx < Gn) {
        eps[idx] = softplus_precise(eta[idx]);
        float o = px_o[idx];
        lsp1[idx] = -softplus_precise(-o) - 1.0f;   // log_sigmoid(o) - 1
        lsn[idx]  = -softplus_precise(o);           // log_sigmoid(-o)
    }
}

__global__ void prep_spots(const float* __restrict__ V,
                           const int* __restrict__ ind_x,
                           unsigned short* __restrict__ vBg,
                           float* __restrict__ v64) {
    int idx = blockIdx.x * 256 + threadIdx.x;   // Bn*64 total, exact
    int b = idx >> 6, l = idx & 63;
    int s = ind_x[b];
    vBg[idx] = f2bf(softplus_precise(V[l * Sn + s]));
    if (idx < Bn) {
        int s2 = ind_x[idx];
        v64[idx] = softplus_precise(V[Ln * Sn + s2]);
    }
}

// prior: parallel, atomicAdd into out[Bn+1] (out pre-zeroed by memset)
__global__ void prior_kernel(const float* __restrict__ eta, float* __restrict__ out) {
    int idx = blockIdx.x * 256 + threadIdx.x;
    float s = 0.f;
    if (idx < Gn) {
        float e = eta[idx];
        s = 0.9189385332046727f + 0.5f * e * e;
    }
    #pragma unroll
    for (int off = 32; off; off >>= 1) s += __shfl_xor(s, off, 64);
    __shared__ float red[4];
    if ((threadIdx.x & 63) == 0) red[threadIdx.x >> 6] = s;
    __syncthreads();
    if (threadIdx.x == 0) atomicAdd(&out[Bn + 1], red[0] + red[1] + red[2] + red[3]);
}

// ---------- main kernel: barrier-free, all VMEM as dwordx4 ----------
//
// term ~= (s-0.5)ln s - (r-0.5)ln r + x*(lsp-1) + r*lsn - lfact[x],  s = r+x

__global__ __launch_bounds__(256) void main_kernel(
    const int*            __restrict__ x,
    const unsigned short* __restrict__ rhB,
    const unsigned short* __restrict__ vBg,
    const float*          __restrict__ v64,
    const float*          __restrict__ lsp1g,
    const float*          __restrict__ lsng,
    const float*          __restrict__ epsg,
    float*                __restrict__ out) {
    __shared__ float lfact[100];

    const int tid = threadIdx.x;
    if (tid < 100) lfact[tid] = lgamma_pos8((float)tid + 1.0f);
    __syncthreads();

    const int g0 = blockIdx.x * 64;
    const int b0 = blockIdx.y * 64;
    const int wave = tid >> 6, lane = tid & 63;
    const int quad = lane >> 4, ln = lane & 15;
    const int mrow  = wave * 16 + ln;              // A-fragment m index
    const int brow0 = b0 + wave * 16 + quad * 4;   // C rows for this lane

    // x tile: 4 aligned int4 loads (lane's 4 genes are consecutive: g0+ln*4..+3)
    int4 xq[4];
    #pragma unroll
    for (int r = 0; r < 4; r++)
        xq[r] = *(const int4*)(x + (size_t)(brow0 + r) * Gn + g0 + ln * 4);

    // per-gene constants + v64 rows: one float4 each
    const float4 lsp1q = *(const float4*)(lsp1g + g0 + ln * 4);
    const float4 lsnq  = *(const float4*)(lsng  + g0 + ln * 4);
    const float4 epsq  = *(const float4*)(epsg  + g0 + ln * 4);
    const float4 vq    = *(const float4*)(v64 + brow0);

    // A fragments: vBg row (b0+mrow), 16B slices
    const unsigned short* aPtr = vBg + (size_t)(b0 + mrow) * 64 + quad * 8;
    bf16x8 af0 = *(const bf16x8*)(aPtr);
    bf16x8 af1 = *(const bf16x8*)(aPtr + 32);

    // B fragments: permuted rhB rows (column-major MFMA assignment baked in)
    const unsigned short* bPtr = rhB + (size_t)(g0 + ln) * 64 + quad * 8;
    bf16x8 bf_[4][2];
    #pragma unroll
    for (int nb = 0; nb < 4; nb++) {
        bf_[nb][0] = *(const bf16x8*)(bPtr + nb * 1024);
        bf_[nb][1] = *(const bf16x8*)(bPtr + nb * 1024 + 32);
    }

    f32x4 acc[4];
    #pragma unroll
    for (int nb = 0; nb < 4; nb++) acc[nb] = (f32x4){0.f, 0.f, 0.f, 0.f};
    #pragma unroll
    for (int nb = 0; nb < 4; nb++) {
        acc[nb] = __builtin_amdgcn_mfma_f32_16x16x32_bf16(af0, bf_[nb][0], acc[nb], 0, 0, 0);
        acc[nb] = __builtin_amdgcn_mfma_f32_16x16x32_bf16(af1, bf_[nb][1], acc[nb], 0, 0, 0);
    }

    const float vvr[4]  = {vq.x, vq.y, vq.z, vq.w};
    const float lsp1v[4] = {lsp1q.x, lsp1q.y, lsp1q.z, lsp1q.w};
    const float lsnv[4]  = {lsnq.x, lsnq.y, lsnq.z, lsnq.w};
    const float ev4[4]   = {epsq.x, epsq.y, epsq.z, epsq.w};

    float rowpart[4] = {0.f, 0.f, 0.f, 0.f};
    #pragma unroll
    for (int nb = 0; nb < 4; nb++) {
        #pragma unroll
        for (int r = 0; r < 4; r++) {
            // acc[nb][r] is column nb*16+ln = gene g0+ln*4+nb (permuted B)
            const float rr = fmaf(ev4[nb], vvr[r], acc[nb][r]);
            const int   xi = ((const int*)&xq[r])[nb];
            const float xf = (float)xi;
            const float s  = rr + xf;
            float t = fmaf(s - 0.5f, __logf(s), -lfact[xi]);
            t = fmaf(-(rr - 0.5f), __logf(rr), t);
            t = fmaf(xf, lsp1v[nb], t);
            t = fmaf(rr, lsnv[nb], t);
            rowpart[r] += t;
        }
    }

    // reduce over the 16 gene-lanes of each quad, one atomic per row
    #pragma unroll
    for (int r = 0; r < 4; r++) {
        float v = rowpart[r];
        v += __shfl_xor(v, 1, 64);
        v += __shfl_xor(v, 2, 64);
        v += __shfl_xor(v, 4, 64);
        v += __shfl_xor(v, 8, 64);
        if (ln == 0) atomicAdd(&out[brow0 + r], -v);
    }
}

// ---------- launch ----------

extern "C" void kernel_launch(void* const* d_in, const int* in_sizes, int n_in,
                              void* d_out, int out_size, void* d_ws, size_t ws_size,
                              hipStream_t stream) {
    const int*   x     = (const int*)d_in[0];
    const int*   ind_x = (const int*)d_in[2];
    const float* W     = (const float*)d_in[3];
    const float* px_o  = (const float*)d_in[4];
    const float* eta   = (const float*)d_in[5];
    const float* V     = (const float*)d_in[6];
    const float* beta  = (const float*)d_in[7];
    float* out = (float*)d_out;

    // ws layout (bytes):
    char* wsb = (char*)d_ws;
    unsigned short* rhB  = (unsigned short*)(wsb);                    // Gn*64*2 = 2,048,000
    unsigned short* vBg  = (unsigned short*)(wsb + 2048000);          // Bn*64*2 =   524,288
    float*          v64  = (float*)(wsb + 2572288);                   // Bn*4    =    16,384
    float*          lsp1 = (float*)(wsb + 2588672);                   // Gn*4
    float*          lsn  = (float*)(wsb + 2652672);
    float*          eps  = (float*)(wsb + 2716672);

    // zero loss accumulators AND the two scalar slots (prior uses atomicAdd)
    hipMemsetAsync(d_out, 0, (Bn + 2) * sizeof(float), stream);

    prep_genes<<<(Gn * 64) / 256, 256, 0, stream>>>(W, px_o, eta, beta, rhB, lsp1, lsn, eps);
    prep_spots<<<(Bn * 64) / 256, 256, 0, stream>>>(V, ind_x, vBg, v64);
    prior_kernel<<<(Gn + 255) / 256, 256, 0, stream>>>(eta, out);

    dim3 grid(Gn / 64, Bn / 64);   // 250 x 64
    main_kernel<<<grid, 256, 0, stream>>>(x, rhB, vBg, v64, lsp1, lsn, eps, out);
}